// Round 3
// baseline (285.307 us; speedup 1.0000x reference)
//
#include <hip/hip_runtime.h>
#include <math.h>

#define HH 256
#define WW 256
#define VV 192
#define DD 256
#define SS 256

// geometry constants (match reference: linspace(-sqrt2, sqrt2, 256) spacing, DT = 2*sqrt2/256)
#define DSQ2      1.41421356237309504880
#define F_SQ2     ((float)DSQ2)
#define F_DT      ((float)(2.0 * DSQ2 / 256.0))          // integration weight
#define F_INV_DS  ((float)(255.0 / (2.0 * DSQ2)))        // index per world unit
#define F_SIG     ((float)(256.0 * DSQ2 / 255.0))        // pixels per index step

#define TILE 64
#define TPAD 65                                           // 2-way LDS banks both axes

static __device__ __forceinline__ float view_angle(int v) {
    // matches np.linspace(0, pi, 192, endpoint=False): f64 mul then cast
    return (float)((double)v * (3.14159265358979323846 / 192.0));
}

// ---------------------------------------------------------------------------
// Kernel A: PIXEL-DRIVEN forward projection (exact adjoint-weight scatter).
// sino[v,d] = sum_pixels (w00+w01)*img  into d0  and  (w10+w11)*img into d0+1,
// where w's are the same 2x2 bilinear adjoint weights validated in bwd.
// Block = (64x64 image tile) x view. Tile staged in LDS; lanes iterate along
// x or y (per view) so per-lane bin spacing >= 0.5 -> ~2 lanes/bin in the
// LDS ds_add_f32 histogram. One guarded global atomicAdd per bin at the end.
// sacc must be pre-zeroed; final temp = DT*sacc - proj is fused into bwd.
// ---------------------------------------------------------------------------
__global__ __launch_bounds__(256)
void fwd_scatter_kernel(const float* __restrict__ img_all,
                        float* __restrict__ sacc) {
    __shared__ float tile[TILE * TPAD];
    __shared__ float bins[DD];
    const int tx = (blockIdx.x & 3) << 6;
    const int ty = (blockIdx.x >> 2) << 6;
    const int v  = blockIdx.y;
    const int b  = blockIdx.z;
    const int tid = threadIdx.x;

    float sn, cs;
    sincosf(view_angle(v), &sn, &cs);
    const float A = F_SIG * cs, B = F_SIG * sn;

    // stage 64x64 tile: 16 floats/thread, coalesced float4 global loads
    const float* __restrict__ img = img_all + (b << 16) + (ty << 8) + tx;
#pragma unroll
    for (int k = 0; k < 4; ++k) {
        const int g = tid + (k << 8);          // 0..1023 float4-chunks
        const int row = g >> 4;
        const int col = (g & 15) << 2;
        const float4 val = *(const float4*)(img + (row << 8) + col);
        float* dst = tile + row * TPAD + col;
        dst[0] = val.x; dst[1] = val.y; dst[2] = val.z; dst[3] = val.w;
    }
    bins[tid] = 0.0f;
    __syncthreads();

    const bool modeX = (fabsf(sn) >= fabsf(cs));  // lanes along x if d-gradient has x-component
    const int fl = tid & 63;                      // fast (lane) coord
    const int slw = tid >> 6;                     // wave id 0..3

#pragma unroll 4
    for (int i = 0; i < 16; ++i) {
        const int o = (i << 2) | slw;
        const int lx = modeX ? fl : o;
        const int ly = modeX ? o : fl;
        const float val = tile[ly * TPAD + lx];
        const float xw = (float)(tx + lx) * (1.0f / 128.0f) + (0.5f / 128.0f - 1.0f);
        const float yw = (float)(ty + ly) * (1.0f / 128.0f) + (0.5f / 128.0f - 1.0f);
        const float sw = fmaf(-xw, sn, yw * cs);
        const float tw = fmaf( xw, cs, yw * sn);
        const float dc = fmaf(sw, F_INV_DS, 127.5f);
        const float tc = fmaf(tw, F_INV_DS, 127.5f);
        const float d0f = floorf(dc);
        const float t0f = floorf(tc);
        const int d0 = (int)d0f;
        const float fd = dc - d0f;
        const float ft = tc - t0f;

        const float dx00 = fmaf(A, -ft, B * fd);
        const float dyn  = fmaf(A,  fd, B * ft);
        const float dx01 = dx00 + A;
        const float dy01 = B - dyn;
        const float dx10 = dx00 - B;
        const float dy10 = A - dyn;
        const float dx11 = dx01 - B;
        const float dy11 = dy10 + B;

        const float w00 = fmaxf(0.0f, 1.0f - fabsf(dx00)) * fmaxf(0.0f, 1.0f - fabsf(dyn));
        const float w01 = fmaxf(0.0f, 1.0f - fabsf(dx01)) * fmaxf(0.0f, 1.0f - fabsf(dy01));
        const float w10 = fmaxf(0.0f, 1.0f - fabsf(dx10)) * fmaxf(0.0f, 1.0f - fabsf(dy10));
        const float w11 = fmaxf(0.0f, 1.0f - fabsf(dx11)) * fmaxf(0.0f, 1.0f - fabsf(dy11));

        const float wA = (w00 + w01) * val;
        const float wB = (w10 + w11) * val;
        if (wA != 0.0f) atomicAdd(&bins[d0], wA);
        if (wB != 0.0f) atomicAdd(&bins[d0 + 1], wB);
    }
    __syncthreads();

    const float bv = bins[tid];
    if (bv != 0.0f)
        atomicAdd(sacc + ((b * VV + v) << 8) + tid, bv);
}

// ---------------------------------------------------------------------------
// Kernel B: pixel-driven exact adjoint, LDS-staged temp view-segment.
// Stages nv views x 256 bins of temp (= DT*sacc - proj, fused here) into LDS,
// then 2 pixels/thread gather ds_read pairs (d0, d0+1) per view.
// No bounds checks: dc in [0.499, 254.501] always.
// ---------------------------------------------------------------------------
__global__ __launch_bounds__(256)
void bwd_partial_kernel(const float* __restrict__ sacc,
                        const float* __restrict__ proj,
                        float* __restrict__ pacc,
                        int nv, int npix) {
    extern __shared__ float smem[];               // nv*DD temp + nv float4 geom
    float* s_t = smem;
    float4* s_g = (float4*)(smem + nv * DD);
    const int tid = threadIdx.x;
    const int v0 = blockIdx.y * nv;
    const int b  = (int)blockIdx.x >> 7;          // 128 blocks (512 px) per image

    if (tid < nv) {
        float sn, cs;
        sincosf(view_angle(v0 + tid), &sn, &cs);
        s_g[tid] = make_float4(cs, sn, F_SIG * cs, F_SIG * sn);
    }
    {   // stage: s_t = DT*sacc - proj for this image/segment (float4)
        const int base = (b * VV + v0) << 8;
        const int n4 = nv << 6;
        const float4* s4 = (const float4*)(sacc + base);
        const float4* p4 = (const float4*)(proj + base);
        for (int i = tid; i < n4; i += 256) {
            const float4 a = s4[i];
            const float4 p = p4[i];
            float4 r;
            r.x = fmaf(F_DT, a.x, -p.x);
            r.y = fmaf(F_DT, a.y, -p.y);
            r.z = fmaf(F_DT, a.z, -p.z);
            r.w = fmaf(F_DT, a.w, -p.w);
            ((float4*)s_t)[i] = r;
        }
    }
    __syncthreads();

    const int idx = ((int)blockIdx.x << 9) + tid;     // pixel 0; pixel 1 = idx+256
    const int y0 = (idx >> 8) & 255;
    const int x  = idx & 255;
    const float xw  = (float)x  * (1.0f / 128.0f) + (0.5f / 128.0f - 1.0f);
    const float yw0 = (float)y0 * (1.0f / 128.0f) + (0.5f / 128.0f - 1.0f);
    const float yw1 = yw0 + (1.0f / 128.0f);

    float acc0 = 0.0f, acc1 = 0.0f;
    for (int vi = 0; vi < nv; ++vi) {
        const float4 g = s_g[vi];                 // cs, sn, A, B
        const float* __restrict__ row = s_t + (vi << 8);
#pragma unroll
        for (int p = 0; p < 2; ++p) {
            const float yw = p ? yw1 : yw0;
            const float sw = fmaf(-xw, g.y, yw * g.x);
            const float tw = fmaf( xw, g.x, yw * g.y);
            const float dc = fmaf(sw, F_INV_DS, 127.5f);
            const float tc = fmaf(tw, F_INV_DS, 127.5f);
            const float d0f = floorf(dc);
            const float t0f = floorf(tc);
            const int d0 = (int)d0f;
            const float fd = dc - d0f;
            const float ft = tc - t0f;

            const float dx00 = fmaf(g.z, -ft, g.w * fd);
            const float dyn  = fmaf(g.z,  fd, g.w * ft);
            const float dx01 = dx00 + g.z;
            const float dy01 = g.w - dyn;
            const float dx10 = dx00 - g.w;
            const float dy10 = g.z - dyn;
            const float dx11 = dx01 - g.w;
            const float dy11 = dy10 + g.w;

            const float w00 = fmaxf(0.0f, 1.0f - fabsf(dx00)) * fmaxf(0.0f, 1.0f - fabsf(dyn));
            const float w01 = fmaxf(0.0f, 1.0f - fabsf(dx01)) * fmaxf(0.0f, 1.0f - fabsf(dy01));
            const float w10 = fmaxf(0.0f, 1.0f - fabsf(dx10)) * fmaxf(0.0f, 1.0f - fabsf(dy10));
            const float w11 = fmaxf(0.0f, 1.0f - fabsf(dx11)) * fmaxf(0.0f, 1.0f - fabsf(dy11));

            const float rA = row[d0];
            const float rB = row[d0 + 1];
            if (p == 0) {
                acc0 = fmaf(w00 + w01, rA, acc0);
                acc0 = fmaf(w10 + w11, rB, acc0);
            } else {
                acc1 = fmaf(w00 + w01, rA, acc1);
                acc1 = fmaf(w10 + w11, rB, acc1);
            }
        }
    }

    pacc[blockIdx.y * npix + idx] = acc0;
    pacc[blockIdx.y * npix + idx + 256] = acc1;
}

// out = input - weight*DT*sum_seg pacc  (float4 vectorized)
__global__ __launch_bounds__(256)
void combine_kernel(const float* __restrict__ input,
                    const float* __restrict__ pacc,
                    const float* __restrict__ weight,
                    float* __restrict__ out,
                    int nseg, int npix) {
    const int i = blockIdx.x * 256 + threadIdx.x;
    const float4* __restrict__ in4 = (const float4*)input;
    float4* __restrict__ out4 = (float4*)out;
    float4 a = make_float4(0.f, 0.f, 0.f, 0.f);
    for (int s = 0; s < nseg; ++s) {
        const float4 p = ((const float4*)(pacc + (size_t)s * npix))[i];
        a.x += p.x; a.y += p.y; a.z += p.z; a.w += p.w;
    }
    const float c = -weight[0] * F_DT;
    const float4 v = in4[i];
    out4[i] = make_float4(fmaf(c, a.x, v.x), fmaf(c, a.y, v.y),
                          fmaf(c, a.z, v.z), fmaf(c, a.w, v.w));
}

extern "C" void kernel_launch(void* const* d_in, const int* in_sizes, int n_in,
                              void* d_out, int out_size, void* d_ws, size_t ws_size,
                              hipStream_t stream) {
    const float* input  = (const float*)d_in[0];   // [nb, H, W]
    const float* proj   = (const float*)d_in[1];   // [nb, V, D]
    const float* weight = (const float*)d_in[2];   // [1]
    float* out  = (float*)d_out;                   // [nb, H, W]

    const int nb = in_sizes[0] / (HH * WW);        // B*C = 2
    const int npix = nb * HH * WW;
    const size_t sino_bytes = (size_t)nb * VV * DD * sizeof(float);
    float* sacc = (float*)d_ws;
    float* pacc = (float*)((char*)d_ws + sino_bytes);

    // view-segment count: largest of {12,8,6,4} whose pacc fits the workspace
    // (4 is known to fit: round-2 config used the same footprint)
    const int cand[4] = {12, 8, 6, 4};
    int nseg = 4;
    for (int i = 0; i < 4; ++i) {
        if (sino_bytes + (size_t)cand[i] * npix * sizeof(float) <= ws_size) {
            nseg = cand[i];
            break;
        }
    }
    const int nv = VV / nseg;

    hipMemsetAsync(sacc, 0, sino_bytes, stream);
    fwd_scatter_kernel<<<dim3(16, VV, nb), 256, 0, stream>>>(input, sacc);
    const size_t shmem = (size_t)nv * DD * sizeof(float) + (size_t)nv * sizeof(float4);
    bwd_partial_kernel<<<dim3(npix / 512, nseg), 256, shmem, stream>>>(sacc, proj, pacc, nv, npix);
    combine_kernel<<<npix / 1024, 256, 0, stream>>>(input, pacc, weight, out, nseg, npix);
}

// Round 5
// 104.060 us; speedup vs baseline: 2.7417x; 2.7417x over previous
//
#include <hip/hip_runtime.h>
#include <math.h>

#define HH 256
#define WW 256
#define VV 192
#define DD 256
#define SS 256

// geometry (matches reference linspace(-sqrt2,sqrt2,256), DT = 2*sqrt2/256)
#define DSQ2      1.41421356237309504880
#define F_DT      ((float)(2.0 * DSQ2 / 256.0))
#define F_INV_DS  ((float)(255.0 / (2.0 * DSQ2)))        // 90.1562 index per world unit
#define F_SIG     ((float)(256.0 * DSQ2 / 255.0))        // 1.41976 px per index step
#define F_RAD     ((float)(128.0 * DSQ2))                // 181.0193

#define TPITCH 67        // 66 used cols + 1 pad (odd pitch vs 32 banks)
#define NSEG 8
#define NV (VV / NSEG)   // 24 views per bwd segment

static __device__ __forceinline__ float view_angle(int v) {
    // matches np.linspace(0, pi, 192, endpoint=False): f64 mul then cast
    return (float)((double)v * (3.14159265358979323846 / 192.0));
}

// ---------------------------------------------------------------------------
// Kernel A: tile-local sample-driven forward projection, register-accumulated.
// Block = (64x64 image tile, view, image). The (d,t) samples whose bilinear
// floor-corner lies in this tile form a rotated square in index space ->
// d-extent <= 66 bins. lane <-> d (register accumulator), waves <-> t phase.
// Tile + 1-px halo staged in LDS. Epilogue: 4-wave LDS reduce, <=66 global
// atomicAdds into sacc (pre-zeroed).
// ---------------------------------------------------------------------------
__global__ __launch_bounds__(256)
void fwd_tile_kernel(const float* __restrict__ img_all,
                     float* __restrict__ sacc) {
    __shared__ float tile[66 * TPITCH];
    __shared__ float red[4][64];
    const int tx = (blockIdx.x & 3) << 6;
    const int ty = (blockIdx.x >> 2) << 6;
    const int v  = blockIdx.y;
    const int b  = blockIdx.z;
    const int tid  = threadIdx.x;
    const int lane = tid & 63;
    const int wv   = tid >> 6;

    const float* __restrict__ img = img_all + (b << 16);

    // ---- stage 66x66 (global x,y in [tx-1, tx+64] x [ty-1, ty+64], 0 outside) ----
    for (int k = tid; k < 64 * 16; k += 256) {           // interior, float4
        const int r  = k >> 4;                           // 0..63 -> y = ty+r
        const int c4 = (k & 15) << 2;                    // 0..60 -> x = tx+c4
        const float4 val = *(const float4*)(img + ((ty + r) << 8) + tx + c4);
        float* dst = tile + (r + 1) * TPITCH + 1 + c4;
        dst[0] = val.x; dst[1] = val.y; dst[2] = val.z; dst[3] = val.w;
    }
    if (tid < 132) {                                     // vertical halo cols (0, 65)
        const int r  = tid >> 1;                         // 0..65
        const int cc = (tid & 1) ? 65 : 0;
        const int gx = tx - 1 + cc;
        const int gy = ty - 1 + r;
        float vv = 0.0f;
        if ((unsigned)gx < 256u && (unsigned)gy < 256u) vv = img[(gy << 8) + gx];
        tile[r * TPITCH + cc] = vv;
    }
    if (tid < 128) {                                     // horizontal halo rows (0, 65)
        const int cc = 1 + (tid & 63);
        const int r  = (tid >> 6) ? 65 : 0;
        const int gx = tx - 1 + cc;
        const int gy = ty - 1 + r;
        float vv = 0.0f;
        if ((unsigned)gx < 256u && (unsigned)gy < 256u) vv = img[(gy << 8) + gx];
        tile[r * TPITCH + cc] = vv;
    }

    // ---- geometry: pixel(d,t) = (X0 + d*Xd + t*Xt, Y0 + d*Yd + t*Yt) ----
    float sn, cs;
    sincosf(view_angle(v), &sn, &cs);
    const float Xd = -sn * F_SIG, Yd = cs * F_SIG;
    const float Xt =  cs * F_SIG, Yt = sn * F_SIG;
    const float X0 = 127.5f - F_RAD * (cs - sn);
    const float Y0 = 127.5f - F_RAD * (cs + sn);

    // ownership: ix0 in [tx+lox, tx+63] (edge tiles also own the -1 fringe)
    const int lox = (tx == 0) ? -1 : 0;
    const int loy = (ty == 0) ? -1 : 0;
    const unsigned spanx = (unsigned)(64 - lox);
    const unsigned spany = (unsigned)(64 - loy);

    // (d,t) bbox of owned pixel box via the inverse (orthogonal) map
    const float xwl = ((float)(tx + lox) + 0.5f) * (1.0f / 128.0f) - 1.0f;
    const float xwh = ((float)(tx + 64)  + 0.5f) * (1.0f / 128.0f) - 1.0f;
    const float ywl = ((float)(ty + loy) + 0.5f) * (1.0f / 128.0f) - 1.0f;
    const float ywh = ((float)(ty + 64)  + 0.5f) * (1.0f / 128.0f) - 1.0f;
    const float dA = -xwl * sn, dB = -xwh * sn;
    const float dC =  ywl * cs, dDq =  ywh * cs;
    const float tAq =  xwl * cs, tB =  xwh * cs;
    const float tC =  ywl * sn, tD =  ywh * sn;
    const float dcmin = 127.5f + (fminf(dA, dB) + fminf(dC, dDq)) * F_INV_DS;
    const float dcmax = 127.5f + (fmaxf(dA, dB) + fmaxf(dC, dDq)) * F_INV_DS;
    const float tcmin = 127.5f + (fminf(tAq, tB) + fminf(tC, tD)) * F_INV_DS;
    const float tcmax = 127.5f + (fmaxf(tAq, tB) + fmaxf(tC, tD)) * F_INV_DS;
    const int dlo = max(0, (int)ceilf(dcmin - 0.002f));
    const int dhi = min(255, (int)floorf(dcmax + 0.002f));
    const int tlo = max(0, (int)ceilf(tcmin - 0.002f));
    const int thi = min(255, (int)floorf(tcmax + 0.002f));

    __syncthreads();

    const int sbase = (b * VV + v) << 8;
    for (int dbase = dlo; dbase <= dhi; dbase += 64) {   // 1 iter except 45-deg edge tiles
        const int d = dbase + lane;
        float acc = 0.0f;
        // tile-local coords shifted so floor(xc) == LDS col directly
        float xc = fmaf((float)d, Xd, fmaf((float)(tlo + wv), Xt, X0)) - (float)tx + 1.0f;
        float yc = fmaf((float)d, Yd, fmaf((float)(tlo + wv), Yt, Y0)) - (float)ty + 1.0f;
        const float step_x = 4.0f * Xt, step_y = 4.0f * Yt;
#pragma unroll 2
        for (int t = tlo + wv; t <= thi; t += 4) {
            const float xf = floorf(xc);
            const float yf = floorf(yc);
            const int cx = (int)xf;
            const int cy = (int)yf;
            const float fx = xc - xf;
            const float fy = yc - yf;
            if (((unsigned)(cx - 1 - lox) < spanx) & ((unsigned)(cy - 1 - loy) < spany)) {
                const float* p = tile + cy * TPITCH + cx;
                const float v00 = p[0],      v10 = p[1];
                const float v01 = p[TPITCH], v11 = p[TPITCH + 1];
                const float top = fmaf(fx, v10 - v00, v00);
                const float bot = fmaf(fx, v11 - v01, v01);
                acc += fmaf(fy, bot - top, top);
            }
            xc += step_x; yc += step_y;
        }
        red[wv][lane] = acc;
        __syncthreads();
        if (tid < 64) {
            const float s = red[0][tid] + red[1][tid] + red[2][tid] + red[3][tid];
            const int d2 = dbase + tid;
            if (s != 0.0f && d2 <= dhi)
                atomicAdd(sacc + sbase + d2, s);
        }
        __syncthreads();
    }
}

// ---------------------------------------------------------------------------
// Kernel B: pixel-driven exact adjoint, LDS-staged view segment, atomics into
// a single ir accumulator (pre-zeroed). temp = DT*sacc - proj fused in stage.
// No bounds checks: pixel radius 1.40869 -> dc,tc in [0.499,254.501].
// ---------------------------------------------------------------------------
__global__ __launch_bounds__(256)
void bwd_partial_kernel(const float* __restrict__ sacc,
                        const float* __restrict__ proj,
                        float* __restrict__ ir) {
    __shared__ float s_t[NV * DD];
    __shared__ float4 s_g[NV];
    const int tid = threadIdx.x;
    const int v0 = blockIdx.y * NV;
    const int b  = (int)blockIdx.x >> 7;          // 128 blocks (512 px) per image

    if (tid < NV) {
        float sn, cs;
        sincosf(view_angle(v0 + tid), &sn, &cs);
        s_g[tid] = make_float4(cs, sn, F_SIG * cs, F_SIG * sn);
    }
    {   // stage s_t = DT*sacc - proj : NV*DD/4 = 1536 float4 chunks, stride-256
        const int base = (b * VV + v0) << 8;
        const float4* s4 = (const float4*)(sacc + base);
        const float4* p4 = (const float4*)(proj + base);
        for (int i = tid; i < NV * (DD / 4); i += 256) {
            const float4 a = s4[i];
            const float4 p = p4[i];
            float4 r;
            r.x = fmaf(F_DT, a.x, -p.x);
            r.y = fmaf(F_DT, a.y, -p.y);
            r.z = fmaf(F_DT, a.z, -p.z);
            r.w = fmaf(F_DT, a.w, -p.w);
            ((float4*)s_t)[i] = r;
        }
    }
    __syncthreads();

    const int idx = ((int)blockIdx.x << 9) + tid;     // pixel 0; pixel 1 = idx+256
    const int y0 = (idx >> 8) & 255;
    const int x  = idx & 255;
    const float xw  = (float)x  * (1.0f / 128.0f) + (0.5f / 128.0f - 1.0f);
    const float yw0 = (float)y0 * (1.0f / 128.0f) + (0.5f / 128.0f - 1.0f);
    const float yw1 = yw0 + (1.0f / 128.0f);

    float acc0 = 0.0f, acc1 = 0.0f;
    for (int vi = 0; vi < NV; ++vi) {
        const float4 g = s_g[vi];                 // cs, sn, A=sig*cs, B=sig*sn
        const float* __restrict__ row = s_t + (vi << 8);
#pragma unroll
        for (int p = 0; p < 2; ++p) {
            const float yw = p ? yw1 : yw0;
            const float sw = fmaf(-xw, g.y, yw * g.x);
            const float tw = fmaf( xw, g.x, yw * g.y);
            const float dc = fmaf(sw, F_INV_DS, 127.5f);
            const float tc = fmaf(tw, F_INV_DS, 127.5f);
            const float d0f = floorf(dc);
            const float t0f = floorf(tc);
            const int d0 = (int)d0f;
            const float fd = dc - d0f;
            const float ft = tc - t0f;

            const float dx00 = fmaf(g.z, -ft, g.w * fd);
            const float dyn  = fmaf(g.z,  fd, g.w * ft);
            const float dx01 = dx00 + g.z;
            const float dy01 = g.w - dyn;
            const float dx10 = dx00 - g.w;
            const float dy10 = g.z - dyn;
            const float dx11 = dx01 - g.w;
            const float dy11 = dy10 + g.w;

            const float w00 = fmaxf(0.0f, 1.0f - fabsf(dx00)) * fmaxf(0.0f, 1.0f - fabsf(dyn));
            const float w01 = fmaxf(0.0f, 1.0f - fabsf(dx01)) * fmaxf(0.0f, 1.0f - fabsf(dy01));
            const float w10 = fmaxf(0.0f, 1.0f - fabsf(dx10)) * fmaxf(0.0f, 1.0f - fabsf(dy10));
            const float w11 = fmaxf(0.0f, 1.0f - fabsf(dx11)) * fmaxf(0.0f, 1.0f - fabsf(dy11));

            const float rA = row[d0];
            const float rB = row[d0 + 1];
            if (p == 0) {
                acc0 = fmaf(w00 + w01, rA, acc0);
                acc0 = fmaf(w10 + w11, rB, acc0);
            } else {
                acc1 = fmaf(w00 + w01, rA, acc1);
                acc1 = fmaf(w10 + w11, rB, acc1);
            }
        }
    }

    atomicAdd(ir + idx, acc0);
    atomicAdd(ir + idx + 256, acc1);
}

// out = input - weight*DT*ir  (float4 vectorized)
__global__ __launch_bounds__(256)
void combine_kernel(const float* __restrict__ input,
                    const float* __restrict__ ir,
                    const float* __restrict__ weight,
                    float* __restrict__ out) {
    const int i = blockIdx.x * 256 + threadIdx.x;
    const float4 a = ((const float4*)ir)[i];
    const float4 v = ((const float4*)input)[i];
    const float c = -weight[0] * F_DT;
    ((float4*)out)[i] = make_float4(fmaf(c, a.x, v.x), fmaf(c, a.y, v.y),
                                    fmaf(c, a.z, v.z), fmaf(c, a.w, v.w));
}

extern "C" void kernel_launch(void* const* d_in, const int* in_sizes, int n_in,
                              void* d_out, int out_size, void* d_ws, size_t ws_size,
                              hipStream_t stream) {
    const float* input  = (const float*)d_in[0];   // [nb, H, W]
    const float* proj   = (const float*)d_in[1];   // [nb, V, D]
    const float* weight = (const float*)d_in[2];   // [1]
    float* out  = (float*)d_out;                   // [nb, H, W]

    const int nb = in_sizes[0] / (HH * WW);        // B*C = 2
    const int npix = nb * HH * WW;
    const int nsino = nb * VV * DD;
    float* sacc = (float*)d_ws;                    // [nb,V,D] forward accumulator
    float* ir   = sacc + nsino;                    // [nb,H,W] adjoint accumulator

    hipMemsetAsync(d_ws, 0, (size_t)(nsino + npix) * sizeof(float), stream);
    fwd_tile_kernel<<<dim3(16, VV, nb), 256, 0, stream>>>(input, sacc);
    bwd_partial_kernel<<<dim3(npix / 512, NSEG), 256, 0, stream>>>(sacc, proj, ir);
    combine_kernel<<<npix / 1024, 256, 0, stream>>>(input, ir, weight, out);
}

// Round 6
// 102.608 us; speedup vs baseline: 2.7806x; 1.0142x over previous
//
#include <hip/hip_runtime.h>
#include <math.h>

#define HH 256
#define WW 256
#define VV 192
#define DD 256
#define SS 256

// geometry (matches reference linspace(-sqrt2,sqrt2,256), DT = 2*sqrt2/256)
#define DSQ2      1.41421356237309504880
#define F_DT      ((float)(2.0 * DSQ2 / 256.0))
#define F_INV_DS  ((float)(255.0 / (2.0 * DSQ2)))        // 90.1562 index per world unit
#define F_SIG     ((float)(256.0 * DSQ2 / 255.0))        // 1.41976 px per index step
#define F_RAD     ((float)(128.0 * DSQ2))                // 181.0193

#define TPITCH 67        // 66 used cols + 1 pad (odd pitch vs 32 banks)
#define NSEG 16
#define NV (VV / NSEG)   // 12 views per bwd segment -> 12.3 KB LDS -> 8 blocks/CU

static __device__ __forceinline__ float view_angle(int v) {
    // matches np.linspace(0, pi, 192, endpoint=False): f64 mul then cast
    return (float)((double)v * (3.14159265358979323846 / 192.0));
}

// ---------------------------------------------------------------------------
// Kernel A: tile-local sample-driven forward projection, register-accumulated.
// Block = (64x64 image tile, view, image). lane <-> d, waves <-> t phase.
// Tile + 1-px halo staged in LDS. Branchless inner loop (clamped LDS address,
// cndmask on result). Epilogue: per-thread guarded global atomicAdd (4 adds
// per bin per block) — no barriers after staging.
// ---------------------------------------------------------------------------
__global__ __launch_bounds__(256)
void fwd_tile_kernel(const float* __restrict__ img_all,
                     float* __restrict__ sacc) {
    __shared__ float tile[66 * TPITCH];
    const int tx = (blockIdx.x & 3) << 6;
    const int ty = (blockIdx.x >> 2) << 6;
    const int v  = blockIdx.y;
    const int b  = blockIdx.z;
    const int tid  = threadIdx.x;
    const int lane = tid & 63;
    const int wv   = tid >> 6;

    const float* __restrict__ img = img_all + (b << 16);

    // ---- stage 66x66 (global x,y in [tx-1, tx+64] x [ty-1, ty+64], 0 outside) ----
    for (int k = tid; k < 64 * 16; k += 256) {           // interior, float4
        const int r  = k >> 4;                           // 0..63 -> y = ty+r
        const int c4 = (k & 15) << 2;                    // 0..60 -> x = tx+c4
        const float4 val = *(const float4*)(img + ((ty + r) << 8) + tx + c4);
        float* dst = tile + (r + 1) * TPITCH + 1 + c4;
        dst[0] = val.x; dst[1] = val.y; dst[2] = val.z; dst[3] = val.w;
    }
    if (tid < 132) {                                     // vertical halo cols (0, 65)
        const int r  = tid >> 1;                         // 0..65
        const int cc = (tid & 1) ? 65 : 0;
        const int gx = tx - 1 + cc;
        const int gy = ty - 1 + r;
        float vv = 0.0f;
        if ((unsigned)gx < 256u && (unsigned)gy < 256u) vv = img[(gy << 8) + gx];
        tile[r * TPITCH + cc] = vv;
    }
    if (tid < 128) {                                     // horizontal halo rows (0, 65)
        const int cc = 1 + (tid & 63);
        const int r  = (tid >> 6) ? 65 : 0;
        const int gx = tx - 1 + cc;
        const int gy = ty - 1 + r;
        float vv = 0.0f;
        if ((unsigned)gx < 256u && (unsigned)gy < 256u) vv = img[(gy << 8) + gx];
        tile[r * TPITCH + cc] = vv;
    }

    // ---- geometry: pixel(d,t) = (X0 + d*Xd + t*Xt, Y0 + d*Yd + t*Yt) ----
    float sn, cs;
    sincosf(view_angle(v), &sn, &cs);
    const float Xd = -sn * F_SIG, Yd = cs * F_SIG;
    const float Xt =  cs * F_SIG, Yt = sn * F_SIG;
    const float X0 = 127.5f - F_RAD * (cs - sn);
    const float Y0 = 127.5f - F_RAD * (cs + sn);

    // ownership: ix0 in [tx+lox, tx+63] (edge tiles also own the -1 fringe)
    const int lox = (tx == 0) ? -1 : 0;
    const int loy = (ty == 0) ? -1 : 0;
    const unsigned spanx = (unsigned)(64 - lox);
    const unsigned spany = (unsigned)(64 - loy);

    // (d,t) bbox of owned pixel box via the inverse (orthogonal) map
    const float xwl = ((float)(tx + lox) + 0.5f) * (1.0f / 128.0f) - 1.0f;
    const float xwh = ((float)(tx + 64)  + 0.5f) * (1.0f / 128.0f) - 1.0f;
    const float ywl = ((float)(ty + loy) + 0.5f) * (1.0f / 128.0f) - 1.0f;
    const float ywh = ((float)(ty + 64)  + 0.5f) * (1.0f / 128.0f) - 1.0f;
    const float dA = -xwl * sn, dB = -xwh * sn;
    const float dC =  ywl * cs, dDq =  ywh * cs;
    const float tAq =  xwl * cs, tB =  xwh * cs;
    const float tC =  ywl * sn, tD =  ywh * sn;
    const float dcmin = 127.5f + (fminf(dA, dB) + fminf(dC, dDq)) * F_INV_DS;
    const float dcmax = 127.5f + (fmaxf(dA, dB) + fmaxf(dC, dDq)) * F_INV_DS;
    const float tcmin = 127.5f + (fminf(tAq, tB) + fminf(tC, tD)) * F_INV_DS;
    const float tcmax = 127.5f + (fmaxf(tAq, tB) + fmaxf(tC, tD)) * F_INV_DS;
    const int dlo = max(0, (int)ceilf(dcmin - 0.002f));
    const int dhi = min(255, (int)floorf(dcmax + 0.002f));
    const int tlo = max(0, (int)ceilf(tcmin - 0.002f));
    const int thi = min(255, (int)floorf(tcmax + 0.002f));

    __syncthreads();

    const int sbase = (b * VV + v) << 8;
    for (int dbase = dlo; dbase <= dhi; dbase += 64) {   // 1 iter except rare edge tiles
        const int d = dbase + lane;
        float acc = 0.0f;
        // tile-local coords shifted so floor(xc) == LDS col directly
        float xc = fmaf((float)d, Xd, fmaf((float)(tlo + wv), Xt, X0)) - (float)tx + 1.0f;
        float yc = fmaf((float)d, Yd, fmaf((float)(tlo + wv), Yt, Y0)) - (float)ty + 1.0f;
        const float step_x = 4.0f * Xt, step_y = 4.0f * Yt;
#pragma unroll 2
        for (int t = tlo + wv; t <= thi; t += 4) {
            const float xf = floorf(xc);
            const float yf = floorf(yc);
            const int cx = (int)xf;
            const int cy = (int)yf;
            const float fx = xc - xf;
            const float fy = yc - yf;
            const bool ok = (((unsigned)(cx - 1 - lox) < spanx) &
                             ((unsigned)(cy - 1 - loy) < spany));
            const int cxc = min(max(cx, 0), 65);
            const int cyc = min(max(cy, 0), 64);         // +TPITCH row stays <= 65
            const float* p = tile + cyc * TPITCH + cxc;
            const float v00 = p[0],      v10 = p[1];
            const float v01 = p[TPITCH], v11 = p[TPITCH + 1];
            const float top = fmaf(fx, v10 - v00, v00);
            const float bot = fmaf(fx, v11 - v01, v01);
            const float smp = fmaf(fy, bot - top, top);
            acc += ok ? smp : 0.0f;
            xc += step_x; yc += step_y;
        }
        if (acc != 0.0f && d <= dhi)
            atomicAdd(sacc + sbase + d, acc);
    }
}

// ---------------------------------------------------------------------------
// Kernel B: pixel-driven exact adjoint, LDS-staged view segment (NV=12 ->
// 12.3 KB -> 8 blocks/CU, 32 waves/CU), atomics into ir (pre-zeroed).
// temp = DT*sacc - proj fused in stage. No bounds checks (dc in [0.5,254.5]).
// ---------------------------------------------------------------------------
__global__ __launch_bounds__(256, 8)
void bwd_partial_kernel(const float* __restrict__ sacc,
                        const float* __restrict__ proj,
                        float* __restrict__ ir) {
    __shared__ float s_t[NV * DD];
    __shared__ float4 s_g[NV];
    const int tid = threadIdx.x;
    const int v0 = blockIdx.y * NV;
    const int b  = (int)blockIdx.x >> 7;          // 128 blocks (512 px) per image

    if (tid < NV) {
        float sn, cs;
        sincosf(view_angle(v0 + tid), &sn, &cs);
        s_g[tid] = make_float4(cs, sn, F_SIG * cs, F_SIG * sn);
    }
    {   // stage s_t = DT*sacc - proj : NV*DD/4 = 768 float4 chunks, stride-256
        const int base = (b * VV + v0) << 8;
        const float4* s4 = (const float4*)(sacc + base);
        const float4* p4 = (const float4*)(proj + base);
#pragma unroll
        for (int k = 0; k < NV * (DD / 4) / 256; ++k) {
            const int i = tid + (k << 8);
            const float4 a = s4[i];
            const float4 p = p4[i];
            float4 r;
            r.x = fmaf(F_DT, a.x, -p.x);
            r.y = fmaf(F_DT, a.y, -p.y);
            r.z = fmaf(F_DT, a.z, -p.z);
            r.w = fmaf(F_DT, a.w, -p.w);
            ((float4*)s_t)[i] = r;
        }
    }
    __syncthreads();

    const int idx = ((int)blockIdx.x << 9) + tid;     // pixel 0; pixel 1 = idx+256
    const int y0 = (idx >> 8) & 255;
    const int x  = idx & 255;
    const float xw  = (float)x  * (1.0f / 128.0f) + (0.5f / 128.0f - 1.0f);
    const float yw0 = (float)y0 * (1.0f / 128.0f) + (0.5f / 128.0f - 1.0f);
    const float yw1 = yw0 + (1.0f / 128.0f);

    float acc0 = 0.0f, acc1 = 0.0f;
#pragma unroll 2
    for (int vi = 0; vi < NV; ++vi) {
        const float4 g = s_g[vi];                 // cs, sn, A=sig*cs, B=sig*sn
        const float* __restrict__ row = s_t + (vi << 8);
#pragma unroll
        for (int p = 0; p < 2; ++p) {
            const float yw = p ? yw1 : yw0;
            const float sw = fmaf(-xw, g.y, yw * g.x);
            const float tw = fmaf( xw, g.x, yw * g.y);
            const float dc = fmaf(sw, F_INV_DS, 127.5f);
            const float tc = fmaf(tw, F_INV_DS, 127.5f);
            const float d0f = floorf(dc);
            const float t0f = floorf(tc);
            const int d0 = (int)d0f;
            const float fd = dc - d0f;
            const float ft = tc - t0f;

            const float dx00 = fmaf(g.z, -ft, g.w * fd);
            const float dyn  = fmaf(g.z,  fd, g.w * ft);
            const float dx01 = dx00 + g.z;
            const float dy01 = g.w - dyn;
            const float dx10 = dx00 - g.w;
            const float dy10 = g.z - dyn;
            const float dx11 = dx01 - g.w;
            const float dy11 = dy10 + g.w;

            const float w00 = fmaxf(0.0f, 1.0f - fabsf(dx00)) * fmaxf(0.0f, 1.0f - fabsf(dyn));
            const float w01 = fmaxf(0.0f, 1.0f - fabsf(dx01)) * fmaxf(0.0f, 1.0f - fabsf(dy01));
            const float w10 = fmaxf(0.0f, 1.0f - fabsf(dx10)) * fmaxf(0.0f, 1.0f - fabsf(dy10));
            const float w11 = fmaxf(0.0f, 1.0f - fabsf(dx11)) * fmaxf(0.0f, 1.0f - fabsf(dy11));

            const float rA = row[d0];
            const float rB = row[d0 + 1];
            if (p == 0) {
                acc0 = fmaf(w00 + w01, rA, acc0);
                acc0 = fmaf(w10 + w11, rB, acc0);
            } else {
                acc1 = fmaf(w00 + w01, rA, acc1);
                acc1 = fmaf(w10 + w11, rB, acc1);
            }
        }
    }

    atomicAdd(ir + idx, acc0);
    atomicAdd(ir + idx + 256, acc1);
}

// out = input - weight*DT*ir  (float4 vectorized)
__global__ __launch_bounds__(256)
void combine_kernel(const float* __restrict__ input,
                    const float* __restrict__ ir,
                    const float* __restrict__ weight,
                    float* __restrict__ out) {
    const int i = blockIdx.x * 256 + threadIdx.x;
    const float4 a = ((const float4*)ir)[i];
    const float4 v = ((const float4*)input)[i];
    const float c = -weight[0] * F_DT;
    ((float4*)out)[i] = make_float4(fmaf(c, a.x, v.x), fmaf(c, a.y, v.y),
                                    fmaf(c, a.z, v.z), fmaf(c, a.w, v.w));
}

extern "C" void kernel_launch(void* const* d_in, const int* in_sizes, int n_in,
                              void* d_out, int out_size, void* d_ws, size_t ws_size,
                              hipStream_t stream) {
    const float* input  = (const float*)d_in[0];   // [nb, H, W]
    const float* proj   = (const float*)d_in[1];   // [nb, V, D]
    const float* weight = (const float*)d_in[2];   // [1]
    float* out  = (float*)d_out;                   // [nb, H, W]

    const int nb = in_sizes[0] / (HH * WW);        // B*C = 2
    const int npix = nb * HH * WW;
    const int nsino = nb * VV * DD;
    float* sacc = (float*)d_ws;                    // [nb,V,D] forward accumulator
    float* ir   = sacc + nsino;                    // [nb,H,W] adjoint accumulator

    hipMemsetAsync(d_ws, 0, (size_t)(nsino + npix) * sizeof(float), stream);
    fwd_tile_kernel<<<dim3(16, VV, nb), 256, 0, stream>>>(input, sacc);
    bwd_partial_kernel<<<dim3(npix / 512, NSEG), 256, 0, stream>>>(sacc, proj, ir);
    combine_kernel<<<npix / 1024, 256, 0, stream>>>(input, ir, weight, out);
}